// Round 1
// baseline (3705.784 us; speedup 1.0000x reference)
//
#include <hip/hip_runtime.h>
#include <hip/hip_bf16.h>

// ---------------------------------------------------------------------------
// PointNet++ critic forward. All fp32. B=32, N=4096.
// Stage 1: FPS(4096->512), ball(r=0.2,ns=32), MLP 3->64->64->128, max
// Stage 2: FPS(512->128),  ball(r=0.4,ns=64), MLP 131->128->128->256, max
// Stage 3: group-all MLP 259->256->512->1024, max over 128
// FC: 1024->512->256->6
// ---------------------------------------------------------------------------

// ============================ FPS ==========================================
// One block per batch. xyz staged in LDS, dist in registers, one barrier/iter
// (ping-pong partials). Argmax tie-break: smallest index (matches jnp.argmax).
template<int N, int S, int NT, bool CHW>
__global__ __launch_bounds__(NT)
void fps_kernel(const float* __restrict__ xyz, float* __restrict__ new_xyz) {
    constexpr int P  = N / NT;
    constexpr int NW = NT / 64;
    __shared__ float sx[N], sy[N], sz[N];
    __shared__ float rv[2][NW > 1 ? NW : 1];
    __shared__ int   ri[2][NW > 1 ? NW : 1];
    const int b = blockIdx.x, t = threadIdx.x;
    if (CHW) {
        const float* base = xyz + (size_t)b * 3 * N;
        for (int i = t; i < N; i += NT) { sx[i] = base[i]; sy[i] = base[N + i]; sz[i] = base[2 * N + i]; }
    } else {
        const float* base = xyz + (size_t)b * N * 3;
        for (int i = t; i < N; i += NT) { sx[i] = base[i*3]; sy[i] = base[i*3+1]; sz[i] = base[i*3+2]; }
    }
    float dist[P];
    #pragma unroll
    for (int p = 0; p < P; ++p) dist[p] = 1e10f;
    __syncthreads();
    int far = 0;
    float* out = new_xyz + (size_t)b * S * 3;
    for (int j = 0; j < S; ++j) {
        if (t == 0) { out[j*3+0] = sx[far]; out[j*3+1] = sy[far]; out[j*3+2] = sz[far]; }
        const float cx = sx[far], cy = sy[far], cz = sz[far];
        float bv = -1.0f; int bi = 0;
        #pragma unroll
        for (int p = 0; p < P; ++p) {
            const int i = p * NT + t;
            const float dx = sx[i] - cx, dy = sy[i] - cy, dz = sz[i] - cz;
            // match reference rounding exactly: no FMA contraction
            const float d = __fadd_rn(__fadd_rn(__fmul_rn(dx, dx), __fmul_rn(dy, dy)), __fmul_rn(dz, dz));
            const float nd = fminf(dist[p], d);
            dist[p] = nd;
            if (nd > bv) { bv = nd; bi = i; }   // strict > keeps smallest i
        }
        #pragma unroll
        for (int o = 32; o > 0; o >>= 1) {
            const float ov = __shfl_xor(bv, o, 64);
            const int   oi = __shfl_xor(bi, o, 64);
            if (ov > bv || (ov == bv && oi < bi)) { bv = ov; bi = oi; }
        }
        if constexpr (NW > 1) {
            const int w = t >> 6, sl = j & 1;
            if ((t & 63) == 0) { rv[sl][w] = bv; ri[sl][w] = bi; }
            __syncthreads();
            float fv = rv[sl][0]; int fi = ri[sl][0];
            #pragma unroll
            for (int w2 = 1; w2 < NW; ++w2) {
                const float v = rv[sl][w2]; const int i2 = ri[sl][w2];
                if (v > fv || (v == fv && i2 < fi)) { fv = v; fi = i2; }
            }
            far = fi;
        } else {
            far = bi;
        }
    }
}

// ============================ Ball query ===================================
// One wave per centroid; sequential 64-point chunks, ballot + prefix-popcount
// compaction => first NS indices (ascending) with d^2 <= r^2, pad with first.
template<int N, int NS, bool CHW>
__global__ __launch_bounds__(256)
void bq_kernel(float r2, const float* __restrict__ xyz, const float* __restrict__ cen,
               int* __restrict__ gidx, int total, int S) {
    const int wid  = (int)((blockIdx.x * 256 + threadIdx.x) >> 6);
    const int lane = threadIdx.x & 63;
    if (wid >= total) return;
    const int b = wid / S;
    const float cx = cen[(size_t)wid*3+0], cy = cen[(size_t)wid*3+1], cz = cen[(size_t)wid*3+2];
    const float* base = CHW ? (xyz + (size_t)b * 3 * N) : (xyz + (size_t)b * N * 3);
    int* out = gidx + (size_t)wid * NS;
    int cnt = 0, first = -1;
    for (int b0 = 0; b0 < N; b0 += 64) {
        const int i = b0 + lane;
        float x, y, z;
        if (CHW) { x = base[i]; y = base[N + i]; z = base[2 * N + i]; }
        else     { x = base[i*3]; y = base[i*3+1]; z = base[i*3+2]; }
        const float dx = x - cx, dy = y - cy, dz = z - cz;
        const float d = __fadd_rn(__fadd_rn(__fmul_rn(dx, dx), __fmul_rn(dy, dy)), __fmul_rn(dz, dz));
        const bool in = (d <= r2);
        const unsigned long long m = __ballot(in);
        if (first < 0 && m != 0ull) first = b0 + __ffsll((unsigned long long)m) - 1;
        const int pos = cnt + (int)__popcll(m & ((1ull << lane) - 1ull));
        if (in && pos < NS) out[pos] = i;
        cnt += (int)__popcll(m);
        if (cnt >= NS) break;
    }
    if (cnt < NS)
        for (int k = cnt + lane; k < NS; k += 64) out[k] = first;
}

// ============================ MLP stage 1 ==================================
// Fused gather + (3->64->64->128) + max over 32 samples. Weights transposed
// [c][o] in LDS (conflict-free), activations broadcast-read as float4.
__global__ __launch_bounds__(256)
void mlp1_kernel(const float* __restrict__ xyz, const float* __restrict__ l1xyz,
                 const int* __restrict__ gidx,
                 const float* __restrict__ w0, const float* __restrict__ b0,
                 const float* __restrict__ w1, const float* __restrict__ b1,
                 const float* __restrict__ w2, const float* __restrict__ b2,
                 float* __restrict__ l1p) {
    __shared__ __align__(16) float W0t[3*64];
    __shared__ __align__(16) float W1t[64*64];
    __shared__ __align__(16) float W2t[64*128];
    __shared__ float B0[64], B1[64], B2[128];
    __shared__ __align__(16) float g[32*4];
    __shared__ __align__(16) float h1[32*64];
    __shared__ __align__(16) float h2[32*64];
    __shared__ float red[256];
    const int t = threadIdx.x, blk = blockIdx.x;
    const int b = blk >> 6, stile = blk & 63;
    for (int i = t; i < 192;  i += 256) W0t[(i % 3)*64  + (i / 3)]  = w0[i];
    for (int i = t; i < 4096; i += 256) W1t[(i % 64)*64 + (i / 64)] = w1[i];
    for (int i = t; i < 8192; i += 256) W2t[(i % 64)*128 + (i / 64)] = w2[i];
    if (t < 64)  { B0[t] = b0[t]; B1[t] = b1[t]; }
    if (t < 128) B2[t] = b2[t];
    const float* xb = xyz + (size_t)b * 3 * 4096;
    for (int ts = 0; ts < 8; ++ts) {
        const int s = stile * 8 + ts;
        __syncthreads();
        if (t < 96) {
            const int n = t / 3, c = t % 3;
            const int gi = gidx[((size_t)b*512 + s)*32 + n];
            g[n*4 + c] = xb[c*4096 + gi] - l1xyz[((size_t)b*512 + s)*3 + c];
        }
        __syncthreads();
        {   // L1
            const int o = t & 63, ng = t >> 6;
            const float wx = W0t[o], wy = W0t[64 + o], wz = W0t[128 + o], bb = B0[o];
            #pragma unroll
            for (int k = 0; k < 8; ++k) {
                const int n = ng * 8 + k;
                const float z = bb + wx*g[n*4] + wy*g[n*4+1] + wz*g[n*4+2];
                h1[n*64 + o] = fmaxf(z, 0.0f);
            }
        }
        __syncthreads();
        {   // L2 (K=64)
            const int o = t & 63, ng = t >> 6;
            float acc[8];
            #pragma unroll
            for (int k = 0; k < 8; ++k) acc[k] = B1[o];
            for (int c = 0; c < 64; c += 4) {
                const float wv0 = W1t[(c+0)*64+o], wv1 = W1t[(c+1)*64+o];
                const float wv2 = W1t[(c+2)*64+o], wv3 = W1t[(c+3)*64+o];
                #pragma unroll
                for (int k = 0; k < 8; ++k) {
                    const float4 hv = *(const float4*)&h1[(ng*8+k)*64 + c];
                    acc[k] += wv0*hv.x + wv1*hv.y + wv2*hv.z + wv3*hv.w;
                }
            }
            #pragma unroll
            for (int k = 0; k < 8; ++k) h2[(ng*8+k)*64 + o] = fmaxf(acc[k], 0.0f);
        }
        __syncthreads();
        {   // L3 (K=64, O=128) fused relu+max over 16 n each
            const int o = t & 127, half = t >> 7;
            float acc[16];
            #pragma unroll
            for (int k = 0; k < 16; ++k) acc[k] = B2[o];
            for (int c = 0; c < 64; c += 4) {
                const float wv0 = W2t[(c+0)*128+o], wv1 = W2t[(c+1)*128+o];
                const float wv2 = W2t[(c+2)*128+o], wv3 = W2t[(c+3)*128+o];
                #pragma unroll
                for (int k = 0; k < 16; ++k) {
                    const float4 hv = *(const float4*)&h2[(half*16+k)*64 + c];
                    acc[k] += wv0*hv.x + wv1*hv.y + wv2*hv.z + wv3*hv.w;
                }
            }
            float m = 0.0f;
            #pragma unroll
            for (int k = 0; k < 16; ++k) m = fmaxf(m, fmaxf(acc[k], 0.0f));
            red[t] = m;
        }
        __syncthreads();
        if (t < 128) l1p[((size_t)b*512 + s)*128 + t] = fmaxf(red[t], red[t + 128]);
    }
}

// ============================ MLP stage 2 ==================================
__device__ __forceinline__ void dense_layer_128o(
    const float* __restrict__ Wt, const float* __restrict__ bias,
    const float* __restrict__ in, int instride, int K, int t,
    float* __restrict__ outp) {
    const int o = t & 127, nh = t >> 7;
    for (int nb = 0; nb < 4; ++nb) {
        const int n0 = nh * 32 + nb * 8;
        float acc[8];
        const float bb = bias[o];
        #pragma unroll
        for (int k = 0; k < 8; ++k) acc[k] = bb;
        int c = 0;
        for (; c + 4 <= K; c += 4) {
            const float w0 = Wt[(c+0)*128+o], w1 = Wt[(c+1)*128+o];
            const float w2 = Wt[(c+2)*128+o], w3 = Wt[(c+3)*128+o];
            #pragma unroll
            for (int k = 0; k < 8; ++k) {
                const float4 xv = *(const float4*)&in[(n0+k)*instride + c];
                acc[k] += w0*xv.x + w1*xv.y + w2*xv.z + w3*xv.w;
            }
        }
        for (; c < K; ++c) {
            const float w = Wt[c*128+o];
            #pragma unroll
            for (int k = 0; k < 8; ++k) acc[k] += w * in[(n0+k)*instride + c];
        }
        #pragma unroll
        for (int k = 0; k < 8; ++k) outp[(n0+k)*128 + o] = fmaxf(acc[k], 0.0f);
    }
}

__device__ __forceinline__ float dense_layer_max128(
    const float* __restrict__ Wt, const float* __restrict__ bias,
    const float* __restrict__ in, int t) {
    const int o = t & 127, nh = t >> 7;
    float m = 0.0f;
    for (int nb = 0; nb < 4; ++nb) {
        const int n0 = nh * 32 + nb * 8;
        float acc[8];
        const float bb = bias[o];
        #pragma unroll
        for (int k = 0; k < 8; ++k) acc[k] = bb;
        for (int c = 0; c < 128; c += 4) {
            const float w0 = Wt[(c+0)*128+o], w1 = Wt[(c+1)*128+o];
            const float w2 = Wt[(c+2)*128+o], w3 = Wt[(c+3)*128+o];
            #pragma unroll
            for (int k = 0; k < 8; ++k) {
                const float4 xv = *(const float4*)&in[(n0+k)*128 + c];
                acc[k] += w0*xv.x + w1*xv.y + w2*xv.z + w3*xv.w;
            }
        }
        #pragma unroll
        for (int k = 0; k < 8; ++k) m = fmaxf(m, fmaxf(acc[k], 0.0f));
    }
    return m;
}

// one block per centroid (32*128 = 4096 blocks). 131->128->128->256, max(64).
__global__ __launch_bounds__(256)
void mlp2_kernel(const float* __restrict__ l1xyz, const float* __restrict__ l1p,
                 const float* __restrict__ l2xyz, const int* __restrict__ gidx,
                 const float* __restrict__ w0, const float* __restrict__ b0,
                 const float* __restrict__ w1, const float* __restrict__ b1,
                 const float* __restrict__ w2, const float* __restrict__ b2,
                 float* __restrict__ X3) {
    __shared__ __align__(16) float xb[64*132];   // x, later h2 (stride 128)
    __shared__ __align__(16) float h1[64*128];
    __shared__ __align__(16) float Wt[131*128];
    __shared__ float BB[128];
    __shared__ int   sg[64];
    __shared__ float red[256];
    const int t = threadIdx.x, bs = blockIdx.x, b = bs >> 7;
    for (int i = t; i < 128*131; i += 256) { const int o = i/131, c = i - o*131; Wt[c*128+o] = w0[i]; }
    if (t < 128) BB[t] = b0[t];
    if (t < 64)  sg[t] = gidx[(size_t)bs*64 + t];
    __syncthreads();
    const float cx = l2xyz[bs*3+0], cy = l2xyz[bs*3+1], cz = l2xyz[bs*3+2];
    for (int i = t; i < 64*131; i += 256) {
        const int n = i / 131, c = i - n*131;
        const int gp = sg[n];
        float v;
        if (c == 0)      v = l1xyz[((size_t)b*512 + gp)*3 + 0] - cx;
        else if (c == 1) v = l1xyz[((size_t)b*512 + gp)*3 + 1] - cy;
        else if (c == 2) v = l1xyz[((size_t)b*512 + gp)*3 + 2] - cz;
        else             v = l1p[((size_t)b*512 + gp)*128 + (c - 3)];
        xb[n*132 + c] = v;
    }
    __syncthreads();
    dense_layer_128o(Wt, BB, xb, 132, 131, t, h1);
    __syncthreads();
    for (int i = t; i < 128*128; i += 256) { const int o = i >> 7, c = i & 127; Wt[c*128+o] = w1[i]; }
    if (t < 128) BB[t] = b1[t];
    __syncthreads();
    dense_layer_128o(Wt, BB, h1, 128, 128, t, xb);   // h2 -> xb (stride 128)
    __syncthreads();
    float* outp = X3 + (size_t)bs*259 + 3;
    for (int chunk = 0; chunk < 2; ++chunk) {
        for (int i = t; i < 128*128; i += 256) { const int o = i >> 7, c = i & 127; Wt[c*128+o] = w2[chunk*16384 + i]; }
        if (t < 128) BB[t] = b2[chunk*128 + t];
        __syncthreads();
        red[t] = dense_layer_max128(Wt, BB, xb, t);
        __syncthreads();
        if (t < 128) outp[chunk*128 + t] = fmaxf(red[t], red[t + 128]);
        __syncthreads();
    }
}

// ============================ Generic GEMM =================================
// C[m,o] = act(sum_c A[m,c] * W[o,c] + bias[o]); 64x64 tile, 4x4 micro.
template<bool RELU>
__global__ __launch_bounds__(256)
void gemm_kernel(const float* __restrict__ A, const float* __restrict__ W,
                 const float* __restrict__ bias, float* __restrict__ C,
                 int M, int K, int O) {
    __shared__ __align__(16) float At[32*68];
    __shared__ __align__(16) float Wt[32*68];
    const int t = threadIdx.x;
    const int mtile = blockIdx.x * 64, otile = blockIdx.y * 64;
    const int tx = t & 15, ty = t >> 4;
    float acc[4][4];
    #pragma unroll
    for (int i = 0; i < 4; ++i)
        #pragma unroll
        for (int j = 0; j < 4; ++j) acc[i][j] = 0.0f;
    const int kk = t & 31, r0 = t >> 5;
    for (int k0 = 0; k0 < K; k0 += 32) {
        #pragma unroll
        for (int rr = 0; rr < 8; ++rr) {
            const int row = r0 + rr * 8;
            const int m = mtile + row, o = otile + row, k = k0 + kk;
            At[kk*68 + row] = (m < M && k < K) ? A[(size_t)m*K + k] : 0.0f;
            Wt[kk*68 + row] = (o < O && k < K) ? W[(size_t)o*K + k] : 0.0f;
        }
        __syncthreads();
        #pragma unroll
        for (int k2 = 0; k2 < 32; ++k2) {
            const float4 av = *(const float4*)&At[k2*68 + tx*4];
            const float4 wv = *(const float4*)&Wt[k2*68 + ty*4];
            const float a[4] = {av.x, av.y, av.z, av.w};
            const float w[4] = {wv.x, wv.y, wv.z, wv.w};
            #pragma unroll
            for (int i = 0; i < 4; ++i)
                #pragma unroll
                for (int j = 0; j < 4; ++j) acc[i][j] += a[i] * w[j];
        }
        __syncthreads();
    }
    #pragma unroll
    for (int i = 0; i < 4; ++i) {
        const int m = mtile + tx*4 + i;
        if (m >= M) continue;
        #pragma unroll
        for (int j = 0; j < 4; ++j) {
            const int o = otile + ty*4 + j;
            if (o >= O) continue;
            float v = acc[i][j] + bias[o];
            if (RELU) v = fmaxf(v, 0.0f);
            C[(size_t)m*O + o] = v;
        }
    }
}

// ============================ small utilities ==============================
__global__ __launch_bounds__(256)
void concat_coords_kernel(const float* __restrict__ l2xyz, float* __restrict__ X3) {
    const int idx = blockIdx.x * 256 + threadIdx.x;  // 32*128*3
    if (idx >= 12288) return;
    X3[(size_t)(idx/3)*259 + (idx%3)] = l2xyz[idx];
}

__global__ __launch_bounds__(256)
void max128_kernel(const float* __restrict__ Y, float* __restrict__ feat) {
    const int idx = blockIdx.x * 256 + threadIdx.x;  // 32*1024
    const int b = idx >> 10, o = idx & 1023;
    const float* p = Y + (size_t)b * 128 * 1024 + o;
    float m = p[0];
    for (int n = 1; n < 128; ++n) m = fmaxf(m, p[(size_t)n * 1024]);
    feat[idx] = m;
}

// ============================ launch =======================================
extern "C" void kernel_launch(void* const* d_in, const int* in_sizes, int n_in,
                              void* d_out, int out_size, void* d_ws, size_t ws_size,
                              hipStream_t stream) {
    const float* xyz  = (const float*)d_in[0];
    const float* s1w0 = (const float*)d_in[1];  const float* s1b0 = (const float*)d_in[2];
    const float* s1w1 = (const float*)d_in[3];  const float* s1b1 = (const float*)d_in[4];
    const float* s1w2 = (const float*)d_in[5];  const float* s1b2 = (const float*)d_in[6];
    const float* s2w0 = (const float*)d_in[7];  const float* s2b0 = (const float*)d_in[8];
    const float* s2w1 = (const float*)d_in[9];  const float* s2b1 = (const float*)d_in[10];
    const float* s2w2 = (const float*)d_in[11]; const float* s2b2 = (const float*)d_in[12];
    const float* s3w0 = (const float*)d_in[13]; const float* s3b0 = (const float*)d_in[14];
    const float* s3w1 = (const float*)d_in[15]; const float* s3b1 = (const float*)d_in[16];
    const float* s3w2 = (const float*)d_in[17]; const float* s3b2 = (const float*)d_in[18];
    const float* f1w  = (const float*)d_in[19]; const float* f1b  = (const float*)d_in[20];
    const float* f2w  = (const float*)d_in[21]; const float* f2b  = (const float*)d_in[22];
    const float* f3w  = (const float*)d_in[23]; const float* f3b  = (const float*)d_in[24];

    char* ws = (char*)d_ws;
    float* l1_xyz = (float*)(ws + 0);              // 32*512*3
    int*   gidx1  = (int*)  (ws + 196608);         // 32*512*32
    float* l1p    = (float*)(ws + 2293760);        // 32*512*128
    float* l2_xyz = (float*)(ws + 10682368);       // 32*128*3
    int*   gidx2  = (int*)  (ws + 10731520);       // 32*128*64
    float* X3     = (float*)(ws + 11780096);       // 32*128*259
    float* Y1     = (float*)(ws + 16023552);       // 4096*256
    float* Y2     = (float*)(ws + 20217856);       // 4096*512
    float* Y3     = (float*)(ws + 28606464);       // 4096*1024
    float* feat   = (float*)(ws + 45383680);       // 32*1024
    float* fb1    = (float*)(ws + 45514752);       // 32*512
    float* fb2    = (float*)(ws + 45580288);       // 32*256

    // Stage 1
    fps_kernel<4096, 512, 256, true><<<32, 256, 0, stream>>>(xyz, l1_xyz);
    bq_kernel<4096, 32, true><<<4096, 256, 0, stream>>>(
        (float)(0.2 * 0.2), xyz, l1_xyz, gidx1, 32 * 512, 512);
    mlp1_kernel<<<2048, 256, 0, stream>>>(xyz, l1_xyz, gidx1,
        s1w0, s1b0, s1w1, s1b1, s1w2, s1b2, l1p);

    // Stage 2
    fps_kernel<512, 128, 64, false><<<32, 64, 0, stream>>>(l1_xyz, l2_xyz);
    bq_kernel<512, 64, false><<<1024, 256, 0, stream>>>(
        (float)(0.4 * 0.4), l1_xyz, l2_xyz, gidx2, 32 * 128, 128);
    concat_coords_kernel<<<48, 256, 0, stream>>>(l2_xyz, X3);
    mlp2_kernel<<<4096, 256, 0, stream>>>(l1_xyz, l1p, l2_xyz, gidx2,
        s2w0, s2b0, s2w1, s2b1, s2w2, s2b2, X3);

    // Stage 3 (group-all MLP as GEMMs over 4096 rows)
    {
        dim3 g1(64, 4);  gemm_kernel<true><<<g1, 256, 0, stream>>>(X3, s3w0, s3b0, Y1, 4096, 259, 256);
        dim3 g2(64, 8);  gemm_kernel<true><<<g2, 256, 0, stream>>>(Y1, s3w1, s3b1, Y2, 4096, 256, 512);
        dim3 g3(64, 16); gemm_kernel<true><<<g3, 256, 0, stream>>>(Y2, s3w2, s3b2, Y3, 4096, 512, 1024);
    }
    max128_kernel<<<128, 256, 0, stream>>>(Y3, feat);

    // FC head
    {
        dim3 g1(1, 8); gemm_kernel<true><<<g1, 256, 0, stream>>>(feat, f1w, f1b, fb1, 32, 1024, 512);
        dim3 g2(1, 4); gemm_kernel<true><<<g2, 256, 0, stream>>>(fb1, f2w, f2b, fb2, 32, 512, 256);
        dim3 g3(1, 1); gemm_kernel<false><<<g3, 256, 0, stream>>>(fb2, f3w, f3b, (float*)d_out, 32, 256, 6);
    }
    (void)in_sizes; (void)n_in; (void)out_size; (void)ws_size;
}

// Round 2
// 2070.216 us; speedup vs baseline: 1.7900x; 1.7900x over previous
//
#include <hip/hip_runtime.h>
#include <hip/hip_bf16.h>

// ---------------------------------------------------------------------------
// PointNet++ critic forward. All fp32. B=32, N=4096.
// R2: MLP1/MLP2 restructured — weights pre-transposed to c-major float4 chunks
// in global (L2-resident), read coalesced per-lane; activations in LDS; each
// thread computes 4 output channels x 8-16 rows (VALU-bound inner loop).
// Kills the 2.6e8 LDS bank conflicts and the 1-wave/SIMD occupancy floor.
// ---------------------------------------------------------------------------

// ============================ FPS ==========================================
template<int N, int S, int NT, bool CHW>
__global__ __launch_bounds__(NT)
void fps_kernel(const float* __restrict__ xyz, float* __restrict__ new_xyz) {
    constexpr int P  = N / NT;
    constexpr int NW = NT / 64;
    __shared__ float sx[N], sy[N], sz[N];
    __shared__ float rv[2][NW > 1 ? NW : 1];
    __shared__ int   ri[2][NW > 1 ? NW : 1];
    const int b = blockIdx.x, t = threadIdx.x;
    if (CHW) {
        const float* base = xyz + (size_t)b * 3 * N;
        for (int i = t; i < N; i += NT) { sx[i] = base[i]; sy[i] = base[N + i]; sz[i] = base[2 * N + i]; }
    } else {
        const float* base = xyz + (size_t)b * N * 3;
        for (int i = t; i < N; i += NT) { sx[i] = base[i*3]; sy[i] = base[i*3+1]; sz[i] = base[i*3+2]; }
    }
    float dist[P];
    #pragma unroll
    for (int p = 0; p < P; ++p) dist[p] = 1e10f;
    __syncthreads();
    int far = 0;
    float* out = new_xyz + (size_t)b * S * 3;
    for (int j = 0; j < S; ++j) {
        if (t == 0) { out[j*3+0] = sx[far]; out[j*3+1] = sy[far]; out[j*3+2] = sz[far]; }
        const float cx = sx[far], cy = sy[far], cz = sz[far];
        float bv = -1.0f; int bi = 0;
        #pragma unroll
        for (int p = 0; p < P; ++p) {
            const int i = p * NT + t;
            const float dx = sx[i] - cx, dy = sy[i] - cy, dz = sz[i] - cz;
            const float d = __fadd_rn(__fadd_rn(__fmul_rn(dx, dx), __fmul_rn(dy, dy)), __fmul_rn(dz, dz));
            const float nd = fminf(dist[p], d);
            dist[p] = nd;
            if (nd > bv) { bv = nd; bi = i; }
        }
        #pragma unroll
        for (int o = 32; o > 0; o >>= 1) {
            const float ov = __shfl_xor(bv, o, 64);
            const int   oi = __shfl_xor(bi, o, 64);
            if (ov > bv || (ov == bv && oi < bi)) { bv = ov; bi = oi; }
        }
        if constexpr (NW > 1) {
            const int w = t >> 6, sl = j & 1;
            if ((t & 63) == 0) { rv[sl][w] = bv; ri[sl][w] = bi; }
            __syncthreads();
            float fv = rv[sl][0]; int fi = ri[sl][0];
            #pragma unroll
            for (int w2 = 1; w2 < NW; ++w2) {
                const float v = rv[sl][w2]; const int i2 = ri[sl][w2];
                if (v > fv || (v == fv && i2 < fi)) { fv = v; fi = i2; }
            }
            far = fi;
        } else {
            far = bi;
        }
    }
}

// ============================ Ball query ===================================
template<int N, int NS, bool CHW>
__global__ __launch_bounds__(256)
void bq_kernel(float r2, const float* __restrict__ xyz, const float* __restrict__ cen,
               int* __restrict__ gidx, int total, int S) {
    const int wid  = (int)((blockIdx.x * 256 + threadIdx.x) >> 6);
    const int lane = threadIdx.x & 63;
    if (wid >= total) return;
    const int b = wid / S;
    const float cx = cen[(size_t)wid*3+0], cy = cen[(size_t)wid*3+1], cz = cen[(size_t)wid*3+2];
    const float* base = CHW ? (xyz + (size_t)b * 3 * N) : (xyz + (size_t)b * N * 3);
    int* out = gidx + (size_t)wid * NS;
    int cnt = 0, first = -1;
    for (int b0 = 0; b0 < N; b0 += 64) {
        const int i = b0 + lane;
        float x, y, z;
        if (CHW) { x = base[i]; y = base[N + i]; z = base[2 * N + i]; }
        else     { x = base[i*3]; y = base[i*3+1]; z = base[i*3+2]; }
        const float dx = x - cx, dy = y - cy, dz = z - cz;
        const float d = __fadd_rn(__fadd_rn(__fmul_rn(dx, dx), __fmul_rn(dy, dy)), __fmul_rn(dz, dz));
        const bool in = (d <= r2);
        const unsigned long long m = __ballot(in);
        if (first < 0 && m != 0ull) first = b0 + __ffsll((unsigned long long)m) - 1;
        const int pos = cnt + (int)__popcll(m & ((1ull << lane) - 1ull));
        if (in && pos < NS) out[pos] = i;
        cnt += (int)__popcll(m);
        if (cnt >= NS) break;
    }
    if (cnt < NS)
        for (int k = cnt + lane; k < NS; k += 64) out[k] = first;
}

// ==================== weight pre-transpose (c-major float4 chunks) =========
// out[cc*O + o] = float4(w[o][c(4cc)], w[o][c(4cc+1)], w[o][c(4cc+2)], w[o][c(4cc+3)])
// reorder=1 (stage-2 layer 0): channel order = [feats(K-3), coords(3), pad0]
__global__ __launch_bounds__(256)
void wt4_kernel(const float* __restrict__ w, float4* __restrict__ out,
                int O, int K, int KC, int reorder) {
    const int i = blockIdx.x * 256 + threadIdx.x;
    if (i >= KC * O) return;
    const int o = i % O, cc = i / O;
    float v[4];
    #pragma unroll
    for (int u = 0; u < 4; ++u) {
        const int cp = cc * 4 + u;
        int c;
        if (reorder) c = (cp < K - 3) ? cp + 3 : (cp < K ? cp - (K - 3) : -1);
        else         c = (cp < K) ? cp : -1;
        v[u] = (c >= 0) ? w[(size_t)o * K + c] : 0.0f;
    }
    out[(size_t)cc * O + o] = make_float4(v[0], v[1], v[2], v[3]);
}

// ===================== dense layer (global weights, LDS acts) ==============
// 64 rows per block, 256 threads. Each thread: 4 o-channels {q,q+Q,q+2Q,q+3Q},
// RPT=Q/4 rows. Inner: 1 ds_read_b128 feeds 16 FMAs -> VALU-bound.
template<int O, int SIN, int SOUT>
__device__ __forceinline__ void dense_relu(
    const float4* __restrict__ W4, const float* __restrict__ bias,
    const float* __restrict__ in, float* __restrict__ out, int KC, int t) {
    constexpr int Q   = O / 4;
    constexpr int RPT = Q / 4;
    constexpr int NB  = (RPT + 7) / 8;
    constexpr int RB  = RPT < 8 ? RPT : 8;
    const int q = t & (Q - 1);
    const int rg = t / Q;
    const int n0 = rg * RPT;
    float bb[4];
    #pragma unroll
    for (int j = 0; j < 4; ++j) bb[j] = bias[q + Q * j];
    #pragma unroll
    for (int nb = 0; nb < NB; ++nb) {
        float acc[RB][4];
        #pragma unroll
        for (int k = 0; k < RB; ++k)
            #pragma unroll
            for (int j = 0; j < 4; ++j) acc[k][j] = bb[j];
        float4 wc[4];
        #pragma unroll
        for (int j = 0; j < 4; ++j) wc[j] = W4[q + Q * j];
        for (int cc = 0; cc < KC; ++cc) {
            float4 wn[4];
            const int ccn = (cc + 1 < KC) ? cc + 1 : cc;
            #pragma unroll
            for (int j = 0; j < 4; ++j) wn[j] = W4[(size_t)ccn * O + q + Q * j];
            #pragma unroll
            for (int k = 0; k < RB; ++k) {
                const float4 xv = *(const float4*)&in[(n0 + nb * 8 + k) * SIN + cc * 4];
                #pragma unroll
                for (int j = 0; j < 4; ++j)
                    acc[k][j] += wc[j].x * xv.x + wc[j].y * xv.y + wc[j].z * xv.z + wc[j].w * xv.w;
            }
            #pragma unroll
            for (int j = 0; j < 4; ++j) wc[j] = wn[j];
        }
        #pragma unroll
        for (int k = 0; k < RB; ++k)
            #pragma unroll
            for (int j = 0; j < 4; ++j)
                out[(n0 + nb * 8 + k) * SOUT + q + Q * j] = fmaxf(acc[k][j], 0.0f);
    }
}

// Same, but reduce max over this thread's rows into red[rg*O + o].
template<int O, int SIN>
__device__ __forceinline__ void dense_relu_max(
    const float4* __restrict__ W4, const float* __restrict__ bias,
    const float* __restrict__ in, float* __restrict__ red, int KC, int t) {
    constexpr int Q   = O / 4;
    constexpr int RPT = Q / 4;
    constexpr int NB  = (RPT + 7) / 8;
    constexpr int RB  = RPT < 8 ? RPT : 8;
    const int q = t & (Q - 1);
    const int rg = t / Q;
    const int n0 = rg * RPT;
    float bb[4], m[4];
    #pragma unroll
    for (int j = 0; j < 4; ++j) { bb[j] = bias[q + Q * j]; m[j] = 0.0f; }
    #pragma unroll
    for (int nb = 0; nb < NB; ++nb) {
        float acc[RB][4];
        #pragma unroll
        for (int k = 0; k < RB; ++k)
            #pragma unroll
            for (int j = 0; j < 4; ++j) acc[k][j] = bb[j];
        float4 wc[4];
        #pragma unroll
        for (int j = 0; j < 4; ++j) wc[j] = W4[q + Q * j];
        for (int cc = 0; cc < KC; ++cc) {
            float4 wn[4];
            const int ccn = (cc + 1 < KC) ? cc + 1 : cc;
            #pragma unroll
            for (int j = 0; j < 4; ++j) wn[j] = W4[(size_t)ccn * O + q + Q * j];
            #pragma unroll
            for (int k = 0; k < RB; ++k) {
                const float4 xv = *(const float4*)&in[(n0 + nb * 8 + k) * SIN + cc * 4];
                #pragma unroll
                for (int j = 0; j < 4; ++j)
                    acc[k][j] += wc[j].x * xv.x + wc[j].y * xv.y + wc[j].z * xv.z + wc[j].w * xv.w;
            }
            #pragma unroll
            for (int j = 0; j < 4; ++j) wc[j] = wn[j];
        }
        #pragma unroll
        for (int k = 0; k < RB; ++k)
            #pragma unroll
            for (int j = 0; j < 4; ++j) m[j] = fmaxf(m[j], fmaxf(acc[k][j], 0.0f));
    }
    #pragma unroll
    for (int j = 0; j < 4; ++j) red[rg * O + q + Q * j] = m[j];
}

// ============================ MLP stage 1 ==================================
// Block: 2 s-tiles (64 rows). grid (256, 32). LDS ~39KB -> 4 blocks/CU.
__global__ __launch_bounds__(256)
void mlp1_kernel(const float* __restrict__ xyz, const float* __restrict__ l1xyz,
                 const int* __restrict__ gidx,
                 const float4* __restrict__ W40, const float* __restrict__ b0,
                 const float4* __restrict__ W41, const float* __restrict__ b1,
                 const float4* __restrict__ W42, const float* __restrict__ b2,
                 float* __restrict__ l1p) {
    __shared__ __align__(16) float g[64 * 4];
    __shared__ __align__(16) float h1[64 * 68];
    __shared__ __align__(16) float h2[64 * 68];
    __shared__ float red[1024];
    const int t = threadIdx.x;
    const int b = blockIdx.y, s0 = blockIdx.x * 2;
    {   // gather: n = t>>2 (0..63), c = t&3
        const int n = t >> 2, c = t & 3;
        const int s = s0 + (n >> 5);
        const int gi = gidx[((size_t)b * 512 + s) * 32 + (n & 31)];
        float v = 0.0f;
        if (c < 3) v = xyz[(size_t)b * 3 * 4096 + c * 4096 + gi] - l1xyz[((size_t)b * 512 + s) * 3 + c];
        g[n * 4 + c] = v;
    }
    __syncthreads();
    dense_relu<64, 4, 68>(W40, b0, g, h1, 1, t);
    __syncthreads();
    dense_relu<64, 68, 68>(W41, b1, h1, h2, 16, t);
    __syncthreads();
    dense_relu_max<128, 68>(W42, b2, h2, red, 16, t);
    __syncthreads();
    {   // final max across 4 row-groups per tile-half
        const int half = t >> 7, o = t & 127;
        float v = red[(half * 4 + 0) * 128 + o];
        v = fmaxf(v, red[(half * 4 + 1) * 128 + o]);
        v = fmaxf(v, red[(half * 4 + 2) * 128 + o]);
        v = fmaxf(v, red[(half * 4 + 3) * 128 + o]);
        l1p[((size_t)b * 512 + s0 + half) * 128 + o] = v;
    }
}

// ============================ MLP stage 2 ==================================
// Block: 1 centroid (64 rows). 4096 blocks. LDS ~69KB -> 2 blocks/CU.
__global__ __launch_bounds__(256)
void mlp2_kernel(const float* __restrict__ l1xyz, const float* __restrict__ l1p,
                 const float* __restrict__ l2xyz, const int* __restrict__ gidx,
                 const float4* __restrict__ W40, const float* __restrict__ b0,
                 const float4* __restrict__ W41, const float* __restrict__ b1,
                 const float4* __restrict__ W42, const float* __restrict__ b2,
                 float* __restrict__ X3) {
    __shared__ __align__(16) float xb[64 * 132];   // x (feats@0..127, coords@128..130, 0@131); later h2 (stride 128)
    __shared__ __align__(16) float h1[64 * 128];
    __shared__ float red[1024];
    __shared__ int sg[64];
    const int t = threadIdx.x, bs = blockIdx.x, b = bs >> 7;
    if (t < 64) sg[t] = gidx[(size_t)bs * 64 + t];
    __syncthreads();
    {   // gather feats as float4: i over 64 rows x 32 chunks
        for (int i = t; i < 64 * 32; i += 256) {
            const int n = i >> 5, cc = i & 31;
            const float4 v = *(const float4*)&l1p[((size_t)b * 512 + sg[n]) * 128 + cc * 4];
            *(float4*)&xb[n * 132 + cc * 4] = v;
        }
        // coords + pad
        if (t < 192) {
            const int n = t / 3, c = t % 3;
            xb[n * 132 + 128 + c] =
                l1xyz[((size_t)b * 512 + sg[n]) * 3 + c] - l2xyz[(size_t)bs * 3 + c];
        }
        if (t < 64) xb[t * 132 + 131] = 0.0f;
    }
    __syncthreads();
    dense_relu<128, 132, 128>(W40, b0, xb, h1, 33, t);
    __syncthreads();
    dense_relu<128, 128, 128>(W41, b1, h1, xb, 32, t);   // h2 -> xb (stride 128)
    __syncthreads();
    dense_relu_max<256, 128>(W42, b2, xb, red, 32, t);
    __syncthreads();
    {   // final max across 4 row-groups; o = t
        float v = red[t];
        v = fmaxf(v, red[256 + t]);
        v = fmaxf(v, red[512 + t]);
        v = fmaxf(v, red[768 + t]);
        X3[(size_t)bs * 259 + 3 + t] = v;
    }
}

// ============================ Generic GEMM =================================
template<bool RELU>
__global__ __launch_bounds__(256)
void gemm_kernel(const float* __restrict__ A, const float* __restrict__ W,
                 const float* __restrict__ bias, float* __restrict__ C,
                 int M, int K, int O) {
    __shared__ __align__(16) float At[32*68];
    __shared__ __align__(16) float Wt[32*68];
    const int t = threadIdx.x;
    const int mtile = blockIdx.x * 64, otile = blockIdx.y * 64;
    const int tx = t & 15, ty = t >> 4;
    float acc[4][4];
    #pragma unroll
    for (int i = 0; i < 4; ++i)
        #pragma unroll
        for (int j = 0; j < 4; ++j) acc[i][j] = 0.0f;
    const int kk = t & 31, r0 = t >> 5;
    for (int k0 = 0; k0 < K; k0 += 32) {
        #pragma unroll
        for (int rr = 0; rr < 8; ++rr) {
            const int row = r0 + rr * 8;
            const int m = mtile + row, o = otile + row, k = k0 + kk;
            At[kk*68 + row] = (m < M && k < K) ? A[(size_t)m*K + k] : 0.0f;
            Wt[kk*68 + row] = (o < O && k < K) ? W[(size_t)o*K + k] : 0.0f;
        }
        __syncthreads();
        #pragma unroll
        for (int k2 = 0; k2 < 32; ++k2) {
            const float4 av = *(const float4*)&At[k2*68 + tx*4];
            const float4 wv = *(const float4*)&Wt[k2*68 + ty*4];
            const float a[4] = {av.x, av.y, av.z, av.w};
            const float w[4] = {wv.x, wv.y, wv.z, wv.w};
            #pragma unroll
            for (int i = 0; i < 4; ++i)
                #pragma unroll
                for (int j = 0; j < 4; ++j) acc[i][j] += a[i] * w[j];
        }
        __syncthreads();
    }
    #pragma unroll
    for (int i = 0; i < 4; ++i) {
        const int m = mtile + tx*4 + i;
        if (m >= M) continue;
        #pragma unroll
        for (int j = 0; j < 4; ++j) {
            const int o = otile + ty*4 + j;
            if (o >= O) continue;
            float v = acc[i][j] + bias[o];
            if (RELU) v = fmaxf(v, 0.0f);
            C[(size_t)m*O + o] = v;
        }
    }
}

// ============================ small utilities ==============================
__global__ __launch_bounds__(256)
void concat_coords_kernel(const float* __restrict__ l2xyz, float* __restrict__ X3) {
    const int idx = blockIdx.x * 256 + threadIdx.x;  // 32*128*3
    if (idx >= 12288) return;
    X3[(size_t)(idx/3)*259 + (idx%3)] = l2xyz[idx];
}

__global__ __launch_bounds__(256)
void max128_kernel(const float* __restrict__ Y, float* __restrict__ feat) {
    const int idx = blockIdx.x * 256 + threadIdx.x;  // 32*1024
    const int b = idx >> 10, o = idx & 1023;
    const float* p = Y + (size_t)b * 128 * 1024 + o;
    float m = p[0];
    for (int n = 1; n < 128; ++n) m = fmaxf(m, p[(size_t)n * 1024]);
    feat[idx] = m;
}

// ============================ launch =======================================
extern "C" void kernel_launch(void* const* d_in, const int* in_sizes, int n_in,
                              void* d_out, int out_size, void* d_ws, size_t ws_size,
                              hipStream_t stream) {
    const float* xyz  = (const float*)d_in[0];
    const float* s1w0 = (const float*)d_in[1];  const float* s1b0 = (const float*)d_in[2];
    const float* s1w1 = (const float*)d_in[3];  const float* s1b1 = (const float*)d_in[4];
    const float* s1w2 = (const float*)d_in[5];  const float* s1b2 = (const float*)d_in[6];
    const float* s2w0 = (const float*)d_in[7];  const float* s2b0 = (const float*)d_in[8];
    const float* s2w1 = (const float*)d_in[9];  const float* s2b1 = (const float*)d_in[10];
    const float* s2w2 = (const float*)d_in[11]; const float* s2b2 = (const float*)d_in[12];
    const float* s3w0 = (const float*)d_in[13]; const float* s3b0 = (const float*)d_in[14];
    const float* s3w1 = (const float*)d_in[15]; const float* s3b1 = (const float*)d_in[16];
    const float* s3w2 = (const float*)d_in[17]; const float* s3b2 = (const float*)d_in[18];
    const float* f1w  = (const float*)d_in[19]; const float* f1b  = (const float*)d_in[20];
    const float* f2w  = (const float*)d_in[21]; const float* f2b  = (const float*)d_in[22];
    const float* f3w  = (const float*)d_in[23]; const float* f3b  = (const float*)d_in[24];

    char* ws = (char*)d_ws;
    float* l1_xyz = (float*)(ws + 0);              // 32*512*3
    int*   gidx1  = (int*)  (ws + 196608);         // 32*512*32
    float* l1p    = (float*)(ws + 2293760);        // 32*512*128
    float* l2_xyz = (float*)(ws + 10682368);       // 32*128*3
    int*   gidx2  = (int*)  (ws + 10731520);       // 32*128*64
    float* X3     = (float*)(ws + 11780096);       // 32*128*259
    float* Y1     = (float*)(ws + 16023552);       // 4096*256  (also hosts W4 buffers early)
    float* Y2     = (float*)(ws + 20217856);       // 4096*512
    float* Y3     = (float*)(ws + 28606464);       // 4096*1024
    float* feat   = (float*)(ws + 45383680);       // 32*1024
    float* fb1    = (float*)(ws + 45514752);       // 32*512
    float* fb2    = (float*)(ws + 45580288);       // 32*256

    // W4 buffers live in the Y1 region: consumed by mlp1/mlp2 BEFORE gemm1 writes Y1.
    float4* W4s10 = (float4*)(ws + 16023552);      // 1*64
    float4* W4s11 = (float4*)(ws + 16024576);      // 16*64
    float4* W4s12 = (float4*)(ws + 16040960);      // 16*128
    float4* W4s20 = (float4*)(ws + 16073728);      // 33*128
    float4* W4s21 = (float4*)(ws + 16141312);      // 32*128
    float4* W4s22 = (float4*)(ws + 16206848);      // 32*256

    // Pre-transpose weights (tiny, one-time per launch)
    wt4_kernel<<<1,  256, 0, stream>>>(s1w0, W4s10,  64,   3,  1, 0);
    wt4_kernel<<<4,  256, 0, stream>>>(s1w1, W4s11,  64,  64, 16, 0);
    wt4_kernel<<<8,  256, 0, stream>>>(s1w2, W4s12, 128,  64, 16, 0);
    wt4_kernel<<<17, 256, 0, stream>>>(s2w0, W4s20, 128, 131, 33, 1);
    wt4_kernel<<<16, 256, 0, stream>>>(s2w1, W4s21, 128, 128, 32, 0);
    wt4_kernel<<<32, 256, 0, stream>>>(s2w2, W4s22, 256, 128, 32, 0);

    // Stage 1
    fps_kernel<4096, 512, 256, true><<<32, 256, 0, stream>>>(xyz, l1_xyz);
    bq_kernel<4096, 32, true><<<4096, 256, 0, stream>>>(
        (float)(0.2 * 0.2), xyz, l1_xyz, gidx1, 32 * 512, 512);
    {
        dim3 g(256, 32);
        mlp1_kernel<<<g, 256, 0, stream>>>(xyz, l1_xyz, gidx1,
            W4s10, s1b0, W4s11, s1b1, W4s12, s1b2, l1p);
    }

    // Stage 2
    fps_kernel<512, 128, 64, false><<<32, 64, 0, stream>>>(l1_xyz, l2_xyz);
    bq_kernel<512, 64, false><<<1024, 256, 0, stream>>>(
        (float)(0.4 * 0.4), l1_xyz, l2_xyz, gidx2, 32 * 128, 128);
    concat_coords_kernel<<<48, 256, 0, stream>>>(l2_xyz, X3);
    mlp2_kernel<<<4096, 256, 0, stream>>>(l1_xyz, l1p, l2_xyz, gidx2,
        W4s20, s2b0, W4s21, s2b1, W4s22, s2b2, X3);

    // Stage 3 (group-all MLP as GEMMs over 4096 rows)
    {
        dim3 g1(64, 4);  gemm_kernel<true><<<g1, 256, 0, stream>>>(X3, s3w0, s3b0, Y1, 4096, 259, 256);
        dim3 g2(64, 8);  gemm_kernel<true><<<g2, 256, 0, stream>>>(Y1, s3w1, s3b1, Y2, 4096, 256, 512);
        dim3 g3(64, 16); gemm_kernel<true><<<g3, 256, 0, stream>>>(Y2, s3w2, s3b2, Y3, 4096, 512, 1024);
    }
    max128_kernel<<<128, 256, 0, stream>>>(Y3, feat);

    // FC head
    {
        dim3 g1(1, 8); gemm_kernel<true><<<g1, 256, 0, stream>>>(feat, f1w, f1b, fb1, 32, 1024, 512);
        dim3 g2(1, 4); gemm_kernel<true><<<g2, 256, 0, stream>>>(fb1, f2w, f2b, fb2, 32, 512, 256);
        dim3 g3(1, 1); gemm_kernel<false><<<g3, 256, 0, stream>>>(fb2, f3w, f3b, (float*)d_out, 32, 256, 6);
    }
    (void)in_sizes; (void)n_in; (void)out_size; (void)ws_size;
}

// Round 3
// 1750.060 us; speedup vs baseline: 2.1175x; 1.1829x over previous
//
#include <hip/hip_runtime.h>
#include <hip/hip_bf16.h>

// ---------------------------------------------------------------------------
// PointNet++ critic forward. fp32. B=32, N=4096.
// R3: FPS rewritten — float4 LDS coords (1 ds_read_b128/pt), DPP wave argmax
// on packed u64 (dist_bits<<32 | (N-1-i)), lane63 + single barrier cross-wave,
// readlane broadcast for the 1-wave variant. wt4 fused to one kernel; coord
// concat folded into mlp2.
// ---------------------------------------------------------------------------

// ======================= DPP wave64 max-reduce (u64) =======================
template<int CTRL>
__device__ __forceinline__ unsigned long long dpp_mov_u64(unsigned long long x) {
    const int lo = (int)(unsigned)(x & 0xffffffffull);
    const int hi = (int)(unsigned)(x >> 32);
    const int nlo = __builtin_amdgcn_update_dpp(lo, lo, CTRL, 0xf, 0xf, false);
    const int nhi = __builtin_amdgcn_update_dpp(hi, hi, CTRL, 0xf, 0xf, false);
    return ((unsigned long long)(unsigned)nhi << 32) | (unsigned)nlo;
}

// After this, lane 63 holds the max over all 64 lanes. max is idempotent, so
// lanes with no DPP source (old value kept) are harmless.
__device__ __forceinline__ unsigned long long wave_max_u64(unsigned long long x) {
    unsigned long long y;
    y = dpp_mov_u64<0x111>(x); if (y > x) x = y;   // row_shr:1
    y = dpp_mov_u64<0x112>(x); if (y > x) x = y;   // row_shr:2
    y = dpp_mov_u64<0x114>(x); if (y > x) x = y;   // row_shr:4
    y = dpp_mov_u64<0x118>(x); if (y > x) x = y;   // row_shr:8
    y = dpp_mov_u64<0x142>(x); if (y > x) x = y;   // row_bcast:15
    y = dpp_mov_u64<0x143>(x); if (y > x) x = y;   // row_bcast:31
    return x;
}

// ============================ FPS ==========================================
template<int N, int S, int NT, bool CHW>
__global__ __launch_bounds__(NT)
void fps_kernel(const float* __restrict__ xyz, float* __restrict__ new_xyz) {
    constexpr int P  = N / NT;
    constexpr int NW = NT / 64;
    __shared__ __align__(16) float4 sxyz[N];
    __shared__ __align__(16) unsigned long long rv[2][NW > 1 ? NW : 2];
    const int b = blockIdx.x, t = threadIdx.x;
    if (CHW) {
        const float* base = xyz + (size_t)b * 3 * N;
        for (int i = t; i < N; i += NT)
            sxyz[i] = make_float4(base[i], base[N + i], base[2 * N + i], 0.0f);
    } else {
        const float* base = xyz + (size_t)b * N * 3;
        for (int i = t; i < N; i += NT)
            sxyz[i] = make_float4(base[i*3], base[i*3+1], base[i*3+2], 0.0f);
    }
    float dist[P];
    #pragma unroll
    for (int p = 0; p < P; ++p) dist[p] = 1e10f;
    __syncthreads();
    int far = 0;
    float* out = new_xyz + (size_t)b * S * 3;
    for (int j = 0; j < S; ++j) {
        const float4 cen = sxyz[far];            // broadcast b128
        if (t == 0) { out[j*3+0] = cen.x; out[j*3+1] = cen.y; out[j*3+2] = cen.z; }
        float bv = -1.0f; int bi = 0;
        #pragma unroll
        for (int p = 0; p < P; ++p) {
            const int i = p * NT + t;
            const float4 pt = sxyz[i];
            const float dx = pt.x - cen.x, dy = pt.y - cen.y, dz = pt.z - cen.z;
            // match reference rounding exactly: no FMA contraction
            const float d = __fadd_rn(__fadd_rn(__fmul_rn(dx, dx), __fmul_rn(dy, dy)), __fmul_rn(dz, dz));
            const float nd = fminf(dist[p], d);
            dist[p] = nd;
            if (nd > bv) { bv = nd; bi = i; }    // strict > keeps smallest i
        }
        unsigned long long pk =
            ((unsigned long long)__float_as_uint(bv) << 32) | (unsigned)(N - 1 - bi);
        pk = wave_max_u64(pk);
        if constexpr (NW > 1) {
            const int sl = j & 1;
            if ((t & 63) == 63) rv[sl][t >> 6] = pk;
            __syncthreads();
            unsigned long long best = rv[sl][0];
            #pragma unroll
            for (int w = 1; w < NW; ++w) { const unsigned long long v = rv[sl][w]; if (v > best) best = v; }
            far = N - 1 - (int)(best & 0xffffffffull);
        } else {
            far = N - 1 - __builtin_amdgcn_readlane((int)(pk & 0xffffffffull), 63);
        }
    }
}

// ============================ Ball query ===================================
template<int N, int NS, bool CHW>
__global__ __launch_bounds__(256)
void bq_kernel(float r2, const float* __restrict__ xyz, const float* __restrict__ cen,
               int* __restrict__ gidx, int total, int S) {
    const int wid  = (int)((blockIdx.x * 256 + threadIdx.x) >> 6);
    const int lane = threadIdx.x & 63;
    if (wid >= total) return;
    const int b = wid / S;
    const float cx = cen[(size_t)wid*3+0], cy = cen[(size_t)wid*3+1], cz = cen[(size_t)wid*3+2];
    const float* base = CHW ? (xyz + (size_t)b * 3 * N) : (xyz + (size_t)b * N * 3);
    int* out = gidx + (size_t)wid * NS;
    int cnt = 0, first = -1;
    for (int b0 = 0; b0 < N; b0 += 64) {
        const int i = b0 + lane;
        float x, y, z;
        if (CHW) { x = base[i]; y = base[N + i]; z = base[2 * N + i]; }
        else     { x = base[i*3]; y = base[i*3+1]; z = base[i*3+2]; }
        const float dx = x - cx, dy = y - cy, dz = z - cz;
        const float d = __fadd_rn(__fadd_rn(__fmul_rn(dx, dx), __fmul_rn(dy, dy)), __fmul_rn(dz, dz));
        const bool in = (d <= r2);
        const unsigned long long m = __ballot(in);
        if (first < 0 && m != 0ull) first = b0 + __ffsll((unsigned long long)m) - 1;
        const int pos = cnt + (int)__popcll(m & ((1ull << lane) - 1ull));
        if (in && pos < NS) out[pos] = i;
        cnt += (int)__popcll(m);
        if (cnt >= NS) break;
    }
    if (cnt < NS)
        for (int k = cnt + lane; k < NS; k += 64) out[k] = first;
}

// ==================== weight pre-transpose (fused, one launch) =============
__device__ __forceinline__ void wt4_one(const float* __restrict__ w, float4* __restrict__ out,
                                        int O, int K, int reorder, int i) {
    const int o = i % O, cc = i / O;
    float v[4];
    #pragma unroll
    for (int u = 0; u < 4; ++u) {
        const int cp = cc * 4 + u;
        int c;
        if (reorder) c = (cp < K - 3) ? cp + 3 : (cp < K ? cp - (K - 3) : -1);
        else         c = (cp < K) ? cp : -1;
        v[u] = (c >= 0) ? w[(size_t)o * K + c] : 0.0f;
    }
    out[(size_t)cc * O + o] = make_float4(v[0], v[1], v[2], v[3]);
}

__global__ __launch_bounds__(256)
void wt4all_kernel(const float* w10, float4* o10, const float* w11, float4* o11,
                   const float* w12, float4* o12, const float* w20, float4* o20,
                   const float* w21, float4* o21, const float* w22, float4* o22) {
    int i = blockIdx.x * 256 + threadIdx.x;
    if (i < 64)        { wt4_one(w10, o10,  64,   3, 0, i); return; }       i -= 64;
    if (i < 1024)      { wt4_one(w11, o11,  64,  64, 0, i); return; }       i -= 1024;
    if (i < 2048)      { wt4_one(w12, o12, 128,  64, 0, i); return; }       i -= 2048;
    if (i < 4224)      { wt4_one(w20, o20, 128, 131, 1, i); return; }       i -= 4224;
    if (i < 4096)      { wt4_one(w21, o21, 128, 128, 0, i); return; }       i -= 4096;
    if (i < 8192)      { wt4_one(w22, o22, 256, 128, 0, i); return; }
}

// ===================== dense layer (global weights, LDS acts) ==============
template<int O, int SIN, int SOUT>
__device__ __forceinline__ void dense_relu(
    const float4* __restrict__ W4, const float* __restrict__ bias,
    const float* __restrict__ in, float* __restrict__ out, int KC, int t) {
    constexpr int Q   = O / 4;
    constexpr int RPT = Q / 4;
    constexpr int NB  = (RPT + 7) / 8;
    constexpr int RB  = RPT < 8 ? RPT : 8;
    const int q = t & (Q - 1);
    const int rg = t / Q;
    const int n0 = rg * RPT;
    float bb[4];
    #pragma unroll
    for (int j = 0; j < 4; ++j) bb[j] = bias[q + Q * j];
    #pragma unroll
    for (int nb = 0; nb < NB; ++nb) {
        float acc[RB][4];
        #pragma unroll
        for (int k = 0; k < RB; ++k)
            #pragma unroll
            for (int j = 0; j < 4; ++j) acc[k][j] = bb[j];
        float4 wc[4];
        #pragma unroll
        for (int j = 0; j < 4; ++j) wc[j] = W4[q + Q * j];
        for (int cc = 0; cc < KC; ++cc) {
            float4 wn[4];
            const int ccn = (cc + 1 < KC) ? cc + 1 : cc;
            #pragma unroll
            for (int j = 0; j < 4; ++j) wn[j] = W4[(size_t)ccn * O + q + Q * j];
            #pragma unroll
            for (int k = 0; k < RB; ++k) {
                const float4 xv = *(const float4*)&in[(n0 + nb * 8 + k) * SIN + cc * 4];
                #pragma unroll
                for (int j = 0; j < 4; ++j)
                    acc[k][j] += wc[j].x * xv.x + wc[j].y * xv.y + wc[j].z * xv.z + wc[j].w * xv.w;
            }
            #pragma unroll
            for (int j = 0; j < 4; ++j) wc[j] = wn[j];
        }
        #pragma unroll
        for (int k = 0; k < RB; ++k)
            #pragma unroll
            for (int j = 0; j < 4; ++j)
                out[(n0 + nb * 8 + k) * SOUT + q + Q * j] = fmaxf(acc[k][j], 0.0f);
    }
}

template<int O, int SIN>
__device__ __forceinline__ void dense_relu_max(
    const float4* __restrict__ W4, const float* __restrict__ bias,
    const float* __restrict__ in, float* __restrict__ red, int KC, int t) {
    constexpr int Q   = O / 4;
    constexpr int RPT = Q / 4;
    constexpr int NB  = (RPT + 7) / 8;
    constexpr int RB  = RPT < 8 ? RPT : 8;
    const int q = t & (Q - 1);
    const int rg = t / Q;
    const int n0 = rg * RPT;
    float bb[4], m[4];
    #pragma unroll
    for (int j = 0; j < 4; ++j) { bb[j] = bias[q + Q * j]; m[j] = 0.0f; }
    #pragma unroll
    for (int nb = 0; nb < NB; ++nb) {
        float acc[RB][4];
        #pragma unroll
        for (int k = 0; k < RB; ++k)
            #pragma unroll
            for (int j = 0; j < 4; ++j) acc[k][j] = bb[j];
        float4 wc[4];
        #pragma unroll
        for (int j = 0; j < 4; ++j) wc[j] = W4[q + Q * j];
        for (int cc = 0; cc < KC; ++cc) {
            float4 wn[4];
            const int ccn = (cc + 1 < KC) ? cc + 1 : cc;
            #pragma unroll
            for (int j = 0; j < 4; ++j) wn[j] = W4[(size_t)ccn * O + q + Q * j];
            #pragma unroll
            for (int k = 0; k < RB; ++k) {
                const float4 xv = *(const float4*)&in[(n0 + nb * 8 + k) * SIN + cc * 4];
                #pragma unroll
                for (int j = 0; j < 4; ++j)
                    acc[k][j] += wc[j].x * xv.x + wc[j].y * xv.y + wc[j].z * xv.z + wc[j].w * xv.w;
            }
            #pragma unroll
            for (int j = 0; j < 4; ++j) wc[j] = wn[j];
        }
        #pragma unroll
        for (int k = 0; k < RB; ++k)
            #pragma unroll
            for (int j = 0; j < 4; ++j) m[j] = fmaxf(m[j], fmaxf(acc[k][j], 0.0f));
    }
    #pragma unroll
    for (int j = 0; j < 4; ++j) red[rg * O + q + Q * j] = m[j];
}

// ============================ MLP stage 1 ==================================
__global__ __launch_bounds__(256)
void mlp1_kernel(const float* __restrict__ xyz, const float* __restrict__ l1xyz,
                 const int* __restrict__ gidx,
                 const float4* __restrict__ W40, const float* __restrict__ b0,
                 const float4* __restrict__ W41, const float* __restrict__ b1,
                 const float4* __restrict__ W42, const float* __restrict__ b2,
                 float* __restrict__ l1p) {
    __shared__ __align__(16) float g[64 * 4];
    __shared__ __align__(16) float h1[64 * 68];
    __shared__ __align__(16) float h2[64 * 68];
    __shared__ float red[1024];
    const int t = threadIdx.x;
    const int b = blockIdx.y, s0 = blockIdx.x * 2;
    {
        const int n = t >> 2, c = t & 3;
        const int s = s0 + (n >> 5);
        const int gi = gidx[((size_t)b * 512 + s) * 32 + (n & 31)];
        float v = 0.0f;
        if (c < 3) v = xyz[(size_t)b * 3 * 4096 + c * 4096 + gi] - l1xyz[((size_t)b * 512 + s) * 3 + c];
        g[n * 4 + c] = v;
    }
    __syncthreads();
    dense_relu<64, 4, 68>(W40, b0, g, h1, 1, t);
    __syncthreads();
    dense_relu<64, 68, 68>(W41, b1, h1, h2, 16, t);
    __syncthreads();
    dense_relu_max<128, 68>(W42, b2, h2, red, 16, t);
    __syncthreads();
    {
        const int half = t >> 7, o = t & 127;
        float v = red[(half * 4 + 0) * 128 + o];
        v = fmaxf(v, red[(half * 4 + 1) * 128 + o]);
        v = fmaxf(v, red[(half * 4 + 2) * 128 + o]);
        v = fmaxf(v, red[(half * 4 + 3) * 128 + o]);
        l1p[((size_t)b * 512 + s0 + half) * 128 + o] = v;
    }
}

// ============================ MLP stage 2 ==================================
__global__ __launch_bounds__(256)
void mlp2_kernel(const float* __restrict__ l1xyz, const float* __restrict__ l1p,
                 const float* __restrict__ l2xyz, const int* __restrict__ gidx,
                 const float4* __restrict__ W40, const float* __restrict__ b0,
                 const float4* __restrict__ W41, const float* __restrict__ b1,
                 const float4* __restrict__ W42, const float* __restrict__ b2,
                 float* __restrict__ X3) {
    __shared__ __align__(16) float xb[64 * 132];
    __shared__ __align__(16) float h1[64 * 128];
    __shared__ float red[1024];
    __shared__ int sg[64];
    const int t = threadIdx.x, bs = blockIdx.x, b = bs >> 7;
    if (t < 64) sg[t] = gidx[(size_t)bs * 64 + t];
    if (t < 3)  X3[(size_t)bs * 259 + t] = l2xyz[(size_t)bs * 3 + t];   // raw coords
    __syncthreads();
    {
        for (int i = t; i < 64 * 32; i += 256) {
            const int n = i >> 5, cc = i & 31;
            const float4 v = *(const float4*)&l1p[((size_t)b * 512 + sg[n]) * 128 + cc * 4];
            *(float4*)&xb[n * 132 + cc * 4] = v;
        }
        if (t < 192) {
            const int n = t / 3, c = t % 3;
            xb[n * 132 + 128 + c] =
                l1xyz[((size_t)b * 512 + sg[n]) * 3 + c] - l2xyz[(size_t)bs * 3 + c];
        }
        if (t < 64) xb[t * 132 + 131] = 0.0f;
    }
    __syncthreads();
    dense_relu<128, 132, 128>(W40, b0, xb, h1, 33, t);
    __syncthreads();
    dense_relu<128, 128, 128>(W41, b1, h1, xb, 32, t);
    __syncthreads();
    dense_relu_max<256, 128>(W42, b2, xb, red, 32, t);
    __syncthreads();
    {
        float v = red[t];
        v = fmaxf(v, red[256 + t]);
        v = fmaxf(v, red[512 + t]);
        v = fmaxf(v, red[768 + t]);
        X3[(size_t)bs * 259 + 3 + t] = v;
    }
}

// ============================ Generic GEMM =================================
template<bool RELU>
__global__ __launch_bounds__(256)
void gemm_kernel(const float* __restrict__ A, const float* __restrict__ W,
                 const float* __restrict__ bias, float* __restrict__ C,
                 int M, int K, int O) {
    __shared__ __align__(16) float At[32*68];
    __shared__ __align__(16) float Wt[32*68];
    const int t = threadIdx.x;
    const int mtile = blockIdx.x * 64, otile = blockIdx.y * 64;
    const int tx = t & 15, ty = t >> 4;
    float acc[4][4];
    #pragma unroll
    for (int i = 0; i < 4; ++i)
        #pragma unroll
        for (int j = 0; j < 4; ++j) acc[i][j] = 0.0f;
    const int kk = t & 31, r0 = t >> 5;
    for (int k0 = 0; k0 < K; k0 += 32) {
        #pragma unroll
        for (int rr = 0; rr < 8; ++rr) {
            const int row = r0 + rr * 8;
            const int m = mtile + row, o = otile + row, k = k0 + kk;
            At[kk*68 + row] = (m < M && k < K) ? A[(size_t)m*K + k] : 0.0f;
            Wt[kk*68 + row] = (o < O && k < K) ? W[(size_t)o*K + k] : 0.0f;
        }
        __syncthreads();
        #pragma unroll
        for (int k2 = 0; k2 < 32; ++k2) {
            const float4 av = *(const float4*)&At[k2*68 + tx*4];
            const float4 wv = *(const float4*)&Wt[k2*68 + ty*4];
            const float a[4] = {av.x, av.y, av.z, av.w};
            const float w[4] = {wv.x, wv.y, wv.z, wv.w};
            #pragma unroll
            for (int i = 0; i < 4; ++i)
                #pragma unroll
                for (int j = 0; j < 4; ++j) acc[i][j] += a[i] * w[j];
        }
        __syncthreads();
    }
    #pragma unroll
    for (int i = 0; i < 4; ++i) {
        const int m = mtile + tx*4 + i;
        if (m >= M) continue;
        #pragma unroll
        for (int j = 0; j < 4; ++j) {
            const int o = otile + ty*4 + j;
            if (o >= O) continue;
            float v = acc[i][j] + bias[o];
            if (RELU) v = fmaxf(v, 0.0f);
            C[(size_t)m*O + o] = v;
        }
    }
}

// ============================ small utilities ==============================
__global__ __launch_bounds__(256)
void max128_kernel(const float* __restrict__ Y, float* __restrict__ feat) {
    const int idx = blockIdx.x * 256 + threadIdx.x;  // 32*1024
    const int b = idx >> 10, o = idx & 1023;
    const float* p = Y + (size_t)b * 128 * 1024 + o;
    float m = p[0];
    for (int n = 1; n < 128; ++n) m = fmaxf(m, p[(size_t)n * 1024]);
    feat[idx] = m;
}

// ============================ launch =======================================
extern "C" void kernel_launch(void* const* d_in, const int* in_sizes, int n_in,
                              void* d_out, int out_size, void* d_ws, size_t ws_size,
                              hipStream_t stream) {
    const float* xyz  = (const float*)d_in[0];
    const float* s1w0 = (const float*)d_in[1];  const float* s1b0 = (const float*)d_in[2];
    const float* s1w1 = (const float*)d_in[3];  const float* s1b1 = (const float*)d_in[4];
    const float* s1w2 = (const float*)d_in[5];  const float* s1b2 = (const float*)d_in[6];
    const float* s2w0 = (const float*)d_in[7];  const float* s2b0 = (const float*)d_in[8];
    const float* s2w1 = (const float*)d_in[9];  const float* s2b1 = (const float*)d_in[10];
    const float* s2w2 = (const float*)d_in[11]; const float* s2b2 = (const float*)d_in[12];
    const float* s3w0 = (const float*)d_in[13]; const float* s3b0 = (const float*)d_in[14];
    const float* s3w1 = (const float*)d_in[15]; const float* s3b1 = (const float*)d_in[16];
    const float* s3w2 = (const float*)d_in[17]; const float* s3b2 = (const float*)d_in[18];
    const float* f1w  = (const float*)d_in[19]; const float* f1b  = (const float*)d_in[20];
    const float* f2w  = (const float*)d_in[21]; const float* f2b  = (const float*)d_in[22];
    const float* f3w  = (const float*)d_in[23]; const float* f3b  = (const float*)d_in[24];

    char* ws = (char*)d_ws;
    float* l1_xyz = (float*)(ws + 0);              // 32*512*3
    int*   gidx1  = (int*)  (ws + 196608);         // 32*512*32
    float* l1p    = (float*)(ws + 2293760);        // 32*512*128
    float* l2_xyz = (float*)(ws + 10682368);       // 32*128*3
    int*   gidx2  = (int*)  (ws + 10731520);       // 32*128*64
    float* X3     = (float*)(ws + 11780096);       // 32*128*259
    float* Y1     = (float*)(ws + 16023552);       // 4096*256  (also hosts W4 buffers early)
    float* Y2     = (float*)(ws + 20217856);       // 4096*512
    float* Y3     = (float*)(ws + 28606464);       // 4096*1024
    float* feat   = (float*)(ws + 45383680);       // 32*1024
    float* fb1    = (float*)(ws + 45514752);       // 32*512
    float* fb2    = (float*)(ws + 45580288);       // 32*256

    // W4 buffers live in the Y1 region: consumed by mlp1/mlp2 BEFORE gemm1 writes Y1.
    float4* W4s10 = (float4*)(ws + 16023552);      // 1*64
    float4* W4s11 = (float4*)(ws + 16024576);      // 16*64
    float4* W4s12 = (float4*)(ws + 16040960);      // 16*128
    float4* W4s20 = (float4*)(ws + 16073728);      // 33*128
    float4* W4s21 = (float4*)(ws + 16141312);      // 32*128
    float4* W4s22 = (float4*)(ws + 16206848);      // 32*256

    wt4all_kernel<<<77, 256, 0, stream>>>(s1w0, W4s10, s1w1, W4s11, s1w2, W4s12,
                                          s2w0, W4s20, s2w1, W4s21, s2w2, W4s22);

    // Stage 1
    fps_kernel<4096, 512, 256, true><<<32, 256, 0, stream>>>(xyz, l1_xyz);
    bq_kernel<4096, 32, true><<<4096, 256, 0, stream>>>(
        (float)(0.2 * 0.2), xyz, l1_xyz, gidx1, 32 * 512, 512);
    {
        dim3 g(256, 32);
        mlp1_kernel<<<g, 256, 0, stream>>>(xyz, l1_xyz, gidx1,
            W4s10, s1b0, W4s11, s1b1, W4s12, s1b2, l1p);
    }

    // Stage 2
    fps_kernel<512, 128, 64, false><<<32, 64, 0, stream>>>(l1_xyz, l2_xyz);
    bq_kernel<512, 64, false><<<1024, 256, 0, stream>>>(
        (float)(0.4 * 0.4), l1_xyz, l2_xyz, gidx2, 32 * 128, 128);
    mlp2_kernel<<<4096, 256, 0, stream>>>(l1_xyz, l1p, l2_xyz, gidx2,
        W4s20, s2b0, W4s21, s2b1, W4s22, s2b2, X3);

    // Stage 3 (group-all MLP as GEMMs over 4096 rows)
    {
        dim3 g1(64, 4);  gemm_kernel<true><<<g1, 256, 0, stream>>>(X3, s3w0, s3b0, Y1, 4096, 259, 256);
        dim3 g2(64, 8);  gemm_kernel<true><<<g2, 256, 0, stream>>>(Y1, s3w1, s3b1, Y2, 4096, 256, 512);
        dim3 g3(64, 16); gemm_kernel<true><<<g3, 256, 0, stream>>>(Y2, s3w2, s3b2, Y3, 4096, 512, 1024);
    }
    max128_kernel<<<128, 256, 0, stream>>>(Y3, feat);

    // FC head
    {
        dim3 g1(1, 8); gemm_kernel<true><<<g1, 256, 0, stream>>>(feat, f1w, f1b, fb1, 32, 1024, 512);
        dim3 g2(1, 4); gemm_kernel<true><<<g2, 256, 0, stream>>>(fb1, f2w, f2b, fb2, 32, 512, 256);
        dim3 g3(1, 1); gemm_kernel<false><<<g3, 256, 0, stream>>>(fb2, f3w, f3b, (float*)d_out, 32, 256, 6);
    }
    (void)in_sizes; (void)n_in; (void)out_size; (void)ws_size;
}